// Round 1
// baseline (184.278 us; speedup 1.0000x reference)
//
#include <hip/hip_runtime.h>
#include <hip/hip_bf16.h>

typedef short s16x8 __attribute__((ext_vector_type(8)));
typedef float f32x4 __attribute__((ext_vector_type(4)));
typedef unsigned short u16x8 __attribute__((ext_vector_type(8)));

__device__ __forceinline__ unsigned short f2bf(float f) {
  union { __hip_bfloat16 h; unsigned short u; } cv;
  cv.h = __float2bfloat16(f);
  return cv.u;
}
__device__ __forceinline__ float bf2f(unsigned short u) {
  union { unsigned int i; float f; } cv;
  cv.i = ((unsigned int)u) << 16;
  return cv.f;
}

__device__ __forceinline__ void gload_lds16(const void* g, void* l) {
  __builtin_amdgcn_global_load_lds(
      (const __attribute__((address_space(1))) unsigned int*)g,
      (__attribute__((address_space(3))) unsigned int*)l,
      16, 0, 0);
}

// C (M x N) = A (M x K) * B^T, B is (N x K) row-major ("bt" layout).
// IN_BF16: A/B are bf16 (ushort), staged via global_load_lds.
// else:    A/B are f32, reg-staged with cast to bf16.
// OUT_BF16: C stored as bf16 (ushort), else f32. val *= scale before store.
template <bool IN_BF16, bool OUT_BF16>
__global__ __launch_bounds__(256) void gemm_bt(
    const void* __restrict__ Ag_, const void* __restrict__ Bg_,
    void* __restrict__ Cg_, int N, int K, float scale,
    long long strideA, long long strideB, long long strideC) {
  const int b  = blockIdx.z;
  const int bm = blockIdx.y, bn = blockIdx.x;
  __shared__ unsigned short As[128 * 32];
  __shared__ unsigned short Bs[128 * 32];
  const int tid = threadIdx.x;
  const int l = tid & 63, wid = tid >> 6;
  const int wr = wid >> 1, wc = wid & 1;

  const unsigned short* Abf = nullptr;
  const unsigned short* Bbf = nullptr;
  const float* Af = nullptr;
  const float* Bf = nullptr;
  if constexpr (IN_BF16) {
    Abf = (const unsigned short*)Ag_ + (size_t)b * strideA;
    Bbf = (const unsigned short*)Bg_ + (size_t)b * strideB;
  } else {
    Af = (const float*)Ag_ + (size_t)b * strideA;
    Bf = (const float*)Bg_ + (size_t)b * strideB;
  }

  const int rowA0 = bm * 128, rowB0 = bn * 128;

  f32x4 acc[4][4] = {};

  for (int k0 = 0; k0 < K; k0 += 32) {
    if constexpr (IN_BF16) {
      // 8 chunks of 1 KiB each for A and B; each wave stages 2 of each.
      // chunk c covers rows [c*16, c*16+16); lane l -> row c*16 + (l>>2),
      // k = k0 + (l&3)*8; lands at LDS byte c*1024 + 16*l (linear).
#pragma unroll
      for (int i = 0; i < 2; ++i) {
        const int c = wid * 2 + i;
        gload_lds16(Abf + (size_t)(rowA0 + c * 16 + (l >> 2)) * K + k0 + (l & 3) * 8,
                    &As[c * 512]);
        gload_lds16(Bbf + (size_t)(rowB0 + c * 16 + (l >> 2)) * K + k0 + (l & 3) * 8,
                    &Bs[c * 512]);
      }
    } else {
      // thread t: row = t>>1, 16 consecutive k starting at (t&1)*16
      const int r = tid >> 1, ks = (tid & 1) * 16;
      const float* pa = Af + (size_t)(rowA0 + r) * K + k0 + ks;
      const float* pb = Bf + (size_t)(rowB0 + r) * K + k0 + ks;
#pragma unroll
      for (int i = 0; i < 4; ++i) {
        float4 va = *(const float4*)(pa + 4 * i);
        float4 vb = *(const float4*)(pb + 4 * i);
        ushort4 sa, sb;
        sa.x = f2bf(va.x); sa.y = f2bf(va.y); sa.z = f2bf(va.z); sa.w = f2bf(va.w);
        sb.x = f2bf(vb.x); sb.y = f2bf(vb.y); sb.z = f2bf(vb.z); sb.w = f2bf(vb.w);
        *(ushort4*)&As[r * 32 + ks + 4 * i] = sa;
        *(ushort4*)&Bs[r * 32 + ks + 4 * i] = sb;
      }
    }
    __syncthreads();

    s16x8 af[4], bfr[4];
#pragma unroll
    for (int m = 0; m < 4; ++m)
      af[m] = *(const s16x8*)&As[(wr * 64 + m * 16 + (l & 15)) * 32 + (l >> 4) * 8];
#pragma unroll
    for (int n = 0; n < 4; ++n)
      bfr[n] = *(const s16x8*)&Bs[(wc * 64 + n * 16 + (l & 15)) * 32 + (l >> 4) * 8];
#pragma unroll
    for (int m = 0; m < 4; ++m)
#pragma unroll
      for (int n = 0; n < 4; ++n)
        acc[m][n] = __builtin_amdgcn_mfma_f32_16x16x32_bf16(af[m], bfr[n], acc[m][n], 0, 0, 0);
    __syncthreads();
  }

  // epilogue: C/D layout col = lane&15, row = (lane>>4)*4 + reg
  const int crow0 = bm * 128 + wr * 64, ccol0 = bn * 128 + wc * 64;
  unsigned short* Cst = nullptr;
  float* Cf = nullptr;
  if constexpr (OUT_BF16)
    Cst = (unsigned short*)Cg_ + (size_t)b * strideC;
  else
    Cf = (float*)Cg_ + (size_t)b * strideC;
#pragma unroll
  for (int m = 0; m < 4; ++m) {
#pragma unroll
    for (int n = 0; n < 4; ++n) {
#pragma unroll
      for (int r = 0; r < 4; ++r) {
        const int row = crow0 + m * 16 + ((l >> 4) << 2) + r;
        const int col = ccol0 + n * 16 + (l & 15);
        const float val = acc[m][n][r] * scale;
        if constexpr (OUT_BF16)
          Cst[(size_t)row * N + col] = f2bf(val);
        else
          Cf[(size_t)row * N + col] = val;
      }
    }
  }
}

// H (B, L, D) f32 -> HT (B, D, L) bf16, 64x64 LDS tiles
__global__ __launch_bounds__(256) void transpose_cast(
    const float* __restrict__ H, unsigned short* __restrict__ HT, int L, int D) {
  const int b = blockIdx.z;
  const int l0 = blockIdx.x * 64, d0 = blockIdx.y * 64;
  __shared__ unsigned short tile[64][72];  // pad to 72 to spread banks
  const float* Hb = H + (size_t)b * L * D;
  unsigned short* HTb = HT + (size_t)b * D * L;
  const int t = threadIdx.x;

  const int lr = t >> 2, dc = (t & 3) * 16;
#pragma unroll
  for (int i = 0; i < 4; ++i) {
    float4 v = *(const float4*)(Hb + (size_t)(l0 + lr) * D + d0 + dc + 4 * i);
    ushort4 s;
    s.x = f2bf(v.x); s.y = f2bf(v.y); s.z = f2bf(v.z); s.w = f2bf(v.w);
    *(ushort4*)&tile[lr][dc + 4 * i] = s;
  }
  __syncthreads();

  const int dr = t >> 2, lc = (t & 3) * 16;
  unsigned short o[16];
#pragma unroll
  for (int i = 0; i < 16; ++i) o[i] = tile[lc + i][dr];
  unsigned short* dst = HTb + (size_t)(d0 + dr) * L + l0 + lc;
  *(uint4*)dst = *(uint4*)&o[0];
  *(uint4*)(dst + 8) = *(uint4*)&o[8];
}

// In-place masked softmax over rows of S (B*T rows, L cols, bf16).
__global__ __launch_bounds__(256) void softmax_mask(
    unsigned short* __restrict__ S, const int* __restrict__ mask, int T, int L) {
  const int row = blockIdx.x;       // b*T + t
  const int b = row >> 10;          // T = 1024
  unsigned short* Sr = S + (size_t)row * L;
  const int* mr = mask + (size_t)b * L;
  const int t = threadIdx.x;

  u16x8 raw = *(const u16x8*)(Sr + t * 8);
  int4 m0 = *(const int4*)(mr + t * 8);
  int4 m1 = *(const int4*)(mr + t * 8 + 4);
  int mm[8] = {m0.x, m0.y, m0.z, m0.w, m1.x, m1.y, m1.z, m1.w};

  float v[8];
  float mx = -3.0e38f;
#pragma unroll
  for (int j = 0; j < 8; ++j) {
    v[j] = mm[j] ? -1.0e30f : bf2f(raw[j]);
    mx = fmaxf(mx, v[j]);
  }
#pragma unroll
  for (int off = 32; off; off >>= 1) mx = fmaxf(mx, __shfl_xor(mx, off));
  __shared__ float redmx[4];
  __shared__ float redsm[4];
  if ((t & 63) == 0) redmx[t >> 6] = mx;
  __syncthreads();
  mx = fmaxf(fmaxf(redmx[0], redmx[1]), fmaxf(redmx[2], redmx[3]));

  float s = 0.f;
#pragma unroll
  for (int j = 0; j < 8; ++j) {
    v[j] = __expf(v[j] - mx);
    s += v[j];
  }
#pragma unroll
  for (int off = 32; off; off >>= 1) s += __shfl_xor(s, off);
  if ((t & 63) == 0) redsm[t >> 6] = s;
  __syncthreads();
  s = redsm[0] + redsm[1] + redsm[2] + redsm[3];
  const float inv = 1.0f / s;

  u16x8 o;
#pragma unroll
  for (int j = 0; j < 8; ++j) o[j] = f2bf(v[j] * inv);
  *(u16x8*)(Sr + t * 8) = o;
}

extern "C" void kernel_launch(void* const* d_in, const int* in_sizes, int n_in,
                              void* d_out, int out_size, void* d_ws, size_t ws_size,
                              hipStream_t stream) {
  const float* H  = (const float*)d_in[0];   // (B, L, Dh)
  const float* G  = (const float*)d_in[1];   // (B, T, Dg)
  const int* mask = (const int*)d_in[2];     // (B, L), nonzero = masked
  const float* Wk = (const float*)d_in[3];   // (P, Dh)
  const float* Wq = (const float*)d_in[4];   // (P, Dg)
  float* Z = (float*)d_out;                  // (B, T, Dh)

  const int B = 8, L = 2048, T = 1024, Dh = 1024, Dg = 768, P = 256;
  const float SCALE = 0.0625f;  // 256^-0.5

  char* ws = (char*)d_ws;
  unsigned short* HbfT = (unsigned short*)ws;                                // B*Dh*L bf16 = 32 MiB
  unsigned short* Sbuf = (unsigned short*)(ws + (size_t)32 * 1024 * 1024);   // B*T*L  bf16 = 32 MiB
  unsigned short* Kbuf = (unsigned short*)(ws + (size_t)64 * 1024 * 1024);   // B*L*P  bf16 =  8 MiB
  unsigned short* Qbuf = (unsigned short*)(ws + (size_t)72 * 1024 * 1024);   // B*T*P  bf16 =  4 MiB

  // K = H @ Wk^T  (M = B*L, N = P, K = Dh), f32 in -> bf16 out
  gemm_bt<false, true><<<dim3(P / 128, (B * L) / 128, 1), 256, 0, stream>>>(
      H, Wk, Kbuf, P, Dh, 1.0f, 0, 0, 0);

  // Q = G @ Wq^T  (M = B*T, N = P, K = Dg)
  gemm_bt<false, true><<<dim3(P / 128, (B * T) / 128, 1), 256, 0, stream>>>(
      G, Wq, Qbuf, P, Dg, 1.0f, 0, 0, 0);

  // HbfT = transpose(bf16(H)) per batch: (B, Dh, L)
  transpose_cast<<<dim3(L / 64, Dh / 64, B), 256, 0, stream>>>(H, HbfT, L, Dh);

  // S = Q @ K^T * SCALE  (per batch: M = T, N = L, K = P), bf16 out
  gemm_bt<true, true><<<dim3(L / 128, T / 128, B), 256, 0, stream>>>(
      Qbuf, Kbuf, Sbuf, L, P, SCALE,
      (long long)T * P, (long long)L * P, (long long)T * L);

  // softmax with mask over L, in place on Sbuf
  softmax_mask<<<dim3(B * T), 256, 0, stream>>>(Sbuf, mask, T, L);

  // Z = alpha @ H  (per batch: M = T, N = Dh, K = L), via HbfT "bt", f32 out
  gemm_bt<true, false><<<dim3(Dh / 128, T / 128, B), 256, 0, stream>>>(
      Sbuf, HbfT, Z, Dh, L, 1.0f,
      (long long)T * L, (long long)Dh * L, (long long)T * Dh);
}

// Round 2
// 158.117 us; speedup vs baseline: 1.1655x; 1.1655x over previous
//
#include <hip/hip_runtime.h>
#include <hip/hip_bf16.h>

typedef short s16x8 __attribute__((ext_vector_type(8)));
typedef float f32x4 __attribute__((ext_vector_type(4)));
typedef unsigned short u16x8 __attribute__((ext_vector_type(8)));

__device__ __forceinline__ unsigned short f2bf(float f) {
  union { __hip_bfloat16 h; unsigned short u; } cv;
  cv.h = __float2bfloat16(f);
  return cv.u;
}
__device__ __forceinline__ float bf2f(unsigned short u) {
  union { unsigned int i; float f; } cv;
  cv.i = ((unsigned int)u) << 16;
  return cv.f;
}

__device__ __forceinline__ void gload_lds16(const void* g, void* l) {
  __builtin_amdgcn_global_load_lds(
      (const __attribute__((address_space(1))) unsigned int*)g,
      (__attribute__((address_space(3))) unsigned int*)l,
      16, 0, 0);
}

// Per-batch compaction scan: keep[l] = (mask[l]==0). Writes compacted source
// indices idx[b][0..Lc), Lc[b], Lcp[b] = Lc rounded up to 128.
__global__ __launch_bounds__(256) void mask_scan(
    const int* __restrict__ mask, int* __restrict__ idx,
    int* __restrict__ Lc, int* __restrict__ Lcp) {
  const int b = blockIdx.x;
  const int* mb = mask + (size_t)b * 2048;
  int* ib = idx + (size_t)b * 2048;
  const int t = threadIdx.x;
  __shared__ int tot[256];
  __shared__ int off[257];
  int keep[8], cnt = 0;
#pragma unroll
  for (int j = 0; j < 8; ++j) {
    keep[j] = (mb[t * 8 + j] == 0);
    cnt += keep[j];
  }
  tot[t] = cnt;
  __syncthreads();
  if (t == 0) {
    int s = 0;
    for (int i = 0; i < 256; ++i) { off[i] = s; s += tot[i]; }
    off[256] = s;
  }
  __syncthreads();
  int p = off[t];
#pragma unroll
  for (int j = 0; j < 8; ++j)
    if (keep[j]) ib[p++] = t * 8 + j;
  if (t == 0) {
    Lc[b] = off[256];
    Lcp[b] = (off[256] + 127) & ~127;
  }
}

// Gather unmasked H rows (f32) -> Hc (B, L, Dh) bf16 row-major AND
// HcT (B, Dh, L) bf16 transposed. Rows [Lc, Lcp) zero-filled.
__global__ __launch_bounds__(256) void gather_cast(
    const float* __restrict__ H, const int* __restrict__ idx,
    const int* __restrict__ Lc, const int* __restrict__ Lcp,
    unsigned short* __restrict__ Hc, unsigned short* __restrict__ HcT) {
  const int b = blockIdx.z;
  const int j0 = blockIdx.x * 64, d0 = blockIdx.y * 64;
  if (j0 >= Lcp[b]) return;
  const int lc = Lc[b];
  __shared__ unsigned short tile[64][72];
  const int t = threadIdx.x;

  const int r = t >> 2, dc = (t & 3) * 16;
  const int j = j0 + r;
  const int src = (j < lc) ? idx[(size_t)b * 2048 + j] : -1;
  ushort4 s[4];
  if (src >= 0) {
    const float* p = H + ((size_t)b * 2048 + src) * 1024 + d0 + dc;
#pragma unroll
    for (int i = 0; i < 4; ++i) {
      float4 v = *(const float4*)(p + 4 * i);
      s[i].x = f2bf(v.x); s[i].y = f2bf(v.y); s[i].z = f2bf(v.z); s[i].w = f2bf(v.w);
    }
  } else {
#pragma unroll
    for (int i = 0; i < 4; ++i) { s[i].x = 0; s[i].y = 0; s[i].z = 0; s[i].w = 0; }
  }
  unsigned short* hcrow = Hc + ((size_t)b * 2048 + j) * 1024 + d0 + dc;
#pragma unroll
  for (int i = 0; i < 4; ++i) {
    *(ushort4*)&tile[r][dc + 4 * i] = s[i];
    *(ushort4*)(hcrow + 4 * i) = s[i];
  }
  __syncthreads();

  const int dr = t >> 2, lcc = (t & 3) * 16;
  unsigned short o[16];
#pragma unroll
  for (int i = 0; i < 16; ++i) o[i] = tile[lcc + i][dr];
  unsigned short* dst = HcT + ((size_t)b * 1024 + d0 + dr) * 2048 + j0 + lcc;
  *(uint4*)dst = *(uint4*)&o[0];
  *(uint4*)(dst + 8) = *(uint4*)&o[8];
}

// C (M x N) = A (M x K) * B^T, B is (N x K) row-major ("bt" layout).
// A_BF16/B_BF16: operand staged via global_load_lds (bf16) or reg-staged f32->bf16.
// mExt/nExt: per-batch row/col extents (early block exit). kDyn: per-batch K.
template <bool A_BF16, bool B_BF16, bool OUT_BF16>
__global__ __launch_bounds__(256) void gemm_bt(
    const void* __restrict__ Ag_, const void* __restrict__ Bg_,
    void* __restrict__ Cg_, int N, int Kfix, int lda, int ldb, float scale,
    long long strideA, long long strideB, long long strideC,
    const int* __restrict__ mExt, const int* __restrict__ nExt,
    const int* __restrict__ kDyn) {
  const int b  = blockIdx.z;
  const int bm = blockIdx.y, bn = blockIdx.x;
  if (mExt && bm * 128 >= mExt[b]) return;
  if (nExt && bn * 128 >= nExt[b]) return;
  const int K = kDyn ? kDyn[b] : Kfix;

  __shared__ unsigned short As[128 * 32];
  __shared__ unsigned short Bs[128 * 32];
  const int tid = threadIdx.x;
  const int l = tid & 63, wid = tid >> 6;
  const int wr = wid >> 1, wc = wid & 1;

  const unsigned short* Abf = nullptr;
  const unsigned short* Bbf = nullptr;
  const float* Af = nullptr;
  const float* Bf = nullptr;
  if constexpr (A_BF16) Abf = (const unsigned short*)Ag_ + (size_t)b * strideA;
  else                  Af  = (const float*)Ag_ + (size_t)b * strideA;
  if constexpr (B_BF16) Bbf = (const unsigned short*)Bg_ + (size_t)b * strideB;
  else                  Bf  = (const float*)Bg_ + (size_t)b * strideB;

  const int rowA0 = bm * 128, rowB0 = bn * 128;

  f32x4 acc[4][4] = {};

  for (int k0 = 0; k0 < K; k0 += 32) {
    if constexpr (A_BF16) {
#pragma unroll
      for (int i = 0; i < 2; ++i) {
        const int c = wid * 2 + i;
        gload_lds16(Abf + (size_t)(rowA0 + c * 16 + (l >> 2)) * lda + k0 + (l & 3) * 8,
                    &As[c * 512]);
      }
    } else {
      const int r = tid >> 1, ks = (tid & 1) * 16;
      const float* pa = Af + (size_t)(rowA0 + r) * lda + k0 + ks;
#pragma unroll
      for (int i = 0; i < 4; ++i) {
        float4 va = *(const float4*)(pa + 4 * i);
        ushort4 sa;
        sa.x = f2bf(va.x); sa.y = f2bf(va.y); sa.z = f2bf(va.z); sa.w = f2bf(va.w);
        *(ushort4*)&As[r * 32 + ks + 4 * i] = sa;
      }
    }
    if constexpr (B_BF16) {
#pragma unroll
      for (int i = 0; i < 2; ++i) {
        const int c = wid * 2 + i;
        gload_lds16(Bbf + (size_t)(rowB0 + c * 16 + (l >> 2)) * ldb + k0 + (l & 3) * 8,
                    &Bs[c * 512]);
      }
    } else {
      const int r = tid >> 1, ks = (tid & 1) * 16;
      const float* pb = Bf + (size_t)(rowB0 + r) * ldb + k0 + ks;
#pragma unroll
      for (int i = 0; i < 4; ++i) {
        float4 vb = *(const float4*)(pb + 4 * i);
        ushort4 sb;
        sb.x = f2bf(vb.x); sb.y = f2bf(vb.y); sb.z = f2bf(vb.z); sb.w = f2bf(vb.w);
        *(ushort4*)&Bs[r * 32 + ks + 4 * i] = sb;
      }
    }
    __syncthreads();

    s16x8 af[4], bfr[4];
#pragma unroll
    for (int m = 0; m < 4; ++m)
      af[m] = *(const s16x8*)&As[(wr * 64 + m * 16 + (l & 15)) * 32 + (l >> 4) * 8];
#pragma unroll
    for (int n = 0; n < 4; ++n)
      bfr[n] = *(const s16x8*)&Bs[(wc * 64 + n * 16 + (l & 15)) * 32 + (l >> 4) * 8];
#pragma unroll
    for (int m = 0; m < 4; ++m)
#pragma unroll
      for (int n = 0; n < 4; ++n)
        acc[m][n] = __builtin_amdgcn_mfma_f32_16x16x32_bf16(af[m], bfr[n], acc[m][n], 0, 0, 0);
    __syncthreads();
  }

  const int crow0 = bm * 128 + wr * 64, ccol0 = bn * 128 + wc * 64;
  unsigned short* Cst = nullptr;
  float* Cf = nullptr;
  if constexpr (OUT_BF16)
    Cst = (unsigned short*)Cg_ + (size_t)b * strideC;
  else
    Cf = (float*)Cg_ + (size_t)b * strideC;
#pragma unroll
  for (int m = 0; m < 4; ++m) {
#pragma unroll
    for (int n = 0; n < 4; ++n) {
#pragma unroll
      for (int r = 0; r < 4; ++r) {
        const int row = crow0 + m * 16 + ((l >> 4) << 2) + r;
        const int col = ccol0 + n * 16 + (l & 15);
        const float val = acc[m][n][r] * scale;
        if constexpr (OUT_BF16)
          Cst[(size_t)row * N + col] = f2bf(val);
        else
          Cf[(size_t)row * N + col] = val;
      }
    }
  }
}

// Softmax over compacted cols [0, Lc); cols [Lc, Lcp) get exact 0. No mask read.
__global__ __launch_bounds__(256) void softmax_c(
    unsigned short* __restrict__ S, const int* __restrict__ Lc,
    const int* __restrict__ Lcp) {
  const int row = blockIdx.x;  // b*T + t, T=1024
  const int b = row >> 10;
  unsigned short* Sr = S + (size_t)row * 2048;
  const int lc = Lc[b], lcp = Lcp[b];
  const int t = threadIdx.x;
  const int j0 = t * 8;
  const bool act = j0 < lcp;

  float v[8];
  if (act) {
    u16x8 raw = *(const u16x8*)(Sr + j0);
#pragma unroll
    for (int j = 0; j < 8; ++j) v[j] = (j0 + j < lc) ? bf2f(raw[j]) : -1.0e30f;
  } else {
#pragma unroll
    for (int j = 0; j < 8; ++j) v[j] = -1.0e30f;
  }

  float mx = -3.0e38f;
#pragma unroll
  for (int j = 0; j < 8; ++j) mx = fmaxf(mx, v[j]);
#pragma unroll
  for (int off = 32; off; off >>= 1) mx = fmaxf(mx, __shfl_xor(mx, off));
  __shared__ float redmx[4];
  __shared__ float redsm[4];
  if ((t & 63) == 0) redmx[t >> 6] = mx;
  __syncthreads();
  mx = fmaxf(fmaxf(redmx[0], redmx[1]), fmaxf(redmx[2], redmx[3]));

  float s = 0.f;
#pragma unroll
  for (int j = 0; j < 8; ++j) {
    v[j] = __expf(v[j] - mx);
    s += v[j];
  }
#pragma unroll
  for (int off = 32; off; off >>= 1) s += __shfl_xor(s, off);
  if ((t & 63) == 0) redsm[t >> 6] = s;
  __syncthreads();
  s = redsm[0] + redsm[1] + redsm[2] + redsm[3];
  const float inv = 1.0f / s;

  if (act) {
    u16x8 o;
#pragma unroll
    for (int j = 0; j < 8; ++j) o[j] = f2bf(v[j] * inv);
    *(u16x8*)(Sr + j0) = o;
  }
}

extern "C" void kernel_launch(void* const* d_in, const int* in_sizes, int n_in,
                              void* d_out, int out_size, void* d_ws, size_t ws_size,
                              hipStream_t stream) {
  const float* H  = (const float*)d_in[0];   // (B, L, Dh)
  const float* G  = (const float*)d_in[1];   // (B, T, Dg)
  const int* mask = (const int*)d_in[2];     // (B, L), nonzero = masked
  const float* Wk = (const float*)d_in[3];   // (P, Dh)
  const float* Wq = (const float*)d_in[4];   // (P, Dg)
  float* Z = (float*)d_out;                  // (B, T, Dh)

  const float SCALE = 0.0625f;  // 256^-0.5
  const size_t MiB = 1024 * 1024;

  char* ws = (char*)d_ws;
  unsigned short* HcT  = (unsigned short*)(ws);             // (B, Dh, L)  32 MiB
  unsigned short* Hc   = (unsigned short*)(ws + 32 * MiB);  // (B, L, Dh)  32 MiB
  unsigned short* Sbuf = Hc;  // alias: Hc dead after Kproj, Sbuf written after
  unsigned short* Kc   = (unsigned short*)(ws + 64 * MiB);  // (B, L, P)    8 MiB
  unsigned short* Qbuf = (unsigned short*)(ws + 72 * MiB);  // (B, T, P)    4 MiB
  int* idx = (int*)Qbuf;  // alias: idx dead (after gather) before Qproj writes
  int* Lc  = (int*)(ws + 76 * MiB);
  int* Lcp = Lc + 16;

  // 0) per-batch compaction scan of !mask
  mask_scan<<<dim3(8), 256, 0, stream>>>(mask, idx, Lc, Lcp);

  // 1) gather unmasked H rows -> Hc (bf16) + HcT (bf16 transposed), zero pad
  gather_cast<<<dim3(32, 16, 8), 256, 0, stream>>>(H, idx, Lc, Lcp, Hc, HcT);

  // 2) Kc = Hc @ Wk^T  (per batch: M = Lcp[b], N = 256, K = 1024)
  gemm_bt<true, false, true><<<dim3(2, 16, 8), 256, 0, stream>>>(
      Hc, Wk, Kc, 256, 1024, 1024, 1024, 1.0f,
      (long long)2048 * 1024, 0, (long long)2048 * 256, Lcp, nullptr, nullptr);

  // 3) Q = G @ Wq^T  (M = B*T = 8192, N = 256, K = 768), f32 reg-staged
  gemm_bt<false, false, true><<<dim3(2, 64, 1), 256, 0, stream>>>(
      G, Wq, Qbuf, 256, 768, 768, 768, 1.0f, 0, 0, 0, nullptr, nullptr, nullptr);

  // 4) S = Q @ Kc^T * SCALE  (per batch: M = 1024, N = Lcp[b], K = 256)
  gemm_bt<true, true, true><<<dim3(16, 8, 8), 256, 0, stream>>>(
      Qbuf, Kc, Sbuf, 2048, 256, 256, 256, SCALE,
      (long long)1024 * 256, (long long)2048 * 256, (long long)1024 * 2048,
      nullptr, Lcp, nullptr);

  // 5) softmax over compacted cols, in place
  softmax_c<<<dim3(8 * 1024), 256, 0, stream>>>(Sbuf, Lc, Lcp);

  // 6) Z = alpha @ Hc  (per batch: M = 1024, N = 1024, K = Lcp[b])
  gemm_bt<true, true, false><<<dim3(8, 8, 8), 256, 0, stream>>>(
      Sbuf, HcT, Z, 1024, 0, 2048, 2048, 1.0f,
      (long long)1024 * 2048, (long long)1024 * 2048, (long long)1024 * 1024,
      nullptr, nullptr, Lcp);
}

// Round 3
// 140.703 us; speedup vs baseline: 1.3097x; 1.1238x over previous
//
#include <hip/hip_runtime.h>
#include <hip/hip_bf16.h>

typedef short s16x8 __attribute__((ext_vector_type(8)));
typedef float f32x4 __attribute__((ext_vector_type(4)));
typedef unsigned short u16x8 __attribute__((ext_vector_type(8)));

__device__ __forceinline__ unsigned short f2bf(float f) {
  union { __hip_bfloat16 h; unsigned short u; } cv;
  cv.h = __float2bfloat16(f);
  return cv.u;
}
__device__ __forceinline__ float bf2f(unsigned short u) {
  union { unsigned int i; float f; } cv;
  cv.i = ((unsigned int)u) << 16;
  return cv.f;
}

__device__ __forceinline__ void gload_lds16(const void* g, void* l) {
  __builtin_amdgcn_global_load_lds(
      (const __attribute__((address_space(1))) unsigned int*)g,
      (__attribute__((address_space(3))) unsigned int*)l,
      16, 0, 0);
}

// f32 -> bf16 elementwise cast, float4/ushort4 vectorized, grid-stride.
__global__ __launch_bounds__(256) void cast_bf16(
    const float* __restrict__ src, unsigned short* __restrict__ dst, int n4) {
  for (int i = blockIdx.x * 256 + threadIdx.x; i < n4; i += gridDim.x * 256) {
    float4 v = *(const float4*)(src + (size_t)i * 4);
    ushort4 s;
    s.x = f2bf(v.x); s.y = f2bf(v.y); s.z = f2bf(v.z); s.w = f2bf(v.w);
    *(ushort4*)(dst + (size_t)i * 4) = s;
  }
}

// Per-batch compaction scan: keep[l] = (mask[l]==0).
__global__ __launch_bounds__(256) void mask_scan(
    const int* __restrict__ mask, int* __restrict__ idx,
    int* __restrict__ Lc, int* __restrict__ Lcp) {
  const int b = blockIdx.x;
  const int* mb = mask + (size_t)b * 2048;
  int* ib = idx + (size_t)b * 2048;
  const int t = threadIdx.x;
  __shared__ int tot[256];
  __shared__ int off[257];
  int keep[8], cnt = 0;
#pragma unroll
  for (int j = 0; j < 8; ++j) {
    keep[j] = (mb[t * 8 + j] == 0);
    cnt += keep[j];
  }
  tot[t] = cnt;
  __syncthreads();
  if (t == 0) {
    int s = 0;
    for (int i = 0; i < 256; ++i) { off[i] = s; s += tot[i]; }
    off[256] = s;
  }
  __syncthreads();
  int p = off[t];
#pragma unroll
  for (int j = 0; j < 8; ++j)
    if (keep[j]) ib[p++] = t * 8 + j;
  if (t == 0) {
    Lc[b] = off[256];
    Lcp[b] = (off[256] + 127) & ~127;
  }
}

// Gather unmasked H rows (f32) -> Hc (B, L, Dh) bf16 row-major AND
// HcT (B, Dh, L) bf16 transposed. Rows [Lc, Lcp) zero-filled.
__global__ __launch_bounds__(256) void gather_cast(
    const float* __restrict__ H, const int* __restrict__ idx,
    const int* __restrict__ Lc, const int* __restrict__ Lcp,
    unsigned short* __restrict__ Hc, unsigned short* __restrict__ HcT) {
  const int b = blockIdx.z;
  const int j0 = blockIdx.x * 64, d0 = blockIdx.y * 64;
  if (j0 >= Lcp[b]) return;
  const int lc = Lc[b];
  __shared__ unsigned short tile[64][72];
  const int t = threadIdx.x;

  const int r = t >> 2, dc = (t & 3) * 16;
  const int j = j0 + r;
  const int src = (j < lc) ? idx[(size_t)b * 2048 + j] : -1;
  ushort4 s[4];
  if (src >= 0) {
    const float* p = H + ((size_t)b * 2048 + src) * 1024 + d0 + dc;
#pragma unroll
    for (int i = 0; i < 4; ++i) {
      float4 v = *(const float4*)(p + 4 * i);
      s[i].x = f2bf(v.x); s[i].y = f2bf(v.y); s[i].z = f2bf(v.z); s[i].w = f2bf(v.w);
    }
  } else {
#pragma unroll
    for (int i = 0; i < 4; ++i) { s[i].x = 0; s[i].y = 0; s[i].z = 0; s[i].w = 0; }
  }
  unsigned short* hcrow = Hc + ((size_t)b * 2048 + j) * 1024 + d0 + dc;
#pragma unroll
  for (int i = 0; i < 4; ++i) {
    *(ushort4*)&tile[r][dc + 4 * i] = s[i];
    *(ushort4*)(hcrow + 4 * i) = s[i];
  }
  __syncthreads();

  const int dr = t >> 2, lcc = (t & 3) * 16;
  unsigned short o[16];
#pragma unroll
  for (int i = 0; i < 16; ++i) o[i] = tile[lcc + i][dr];
  unsigned short* dst = HcT + ((size_t)b * 1024 + d0 + dr) * 2048 + j0 + lcc;
  *(uint4*)dst = *(uint4*)&o[0];
  *(uint4*)(dst + 8) = *(uint4*)&o[8];
}

// C (M x N tile 128 x BN) = A (M x K) * B^T, bf16 in via global_load_lds.
// BN in {64, 128}. mExt/nExt: per-batch extents (early exit). kDyn: per-batch K.
template <int BN, bool OUT_BF16>
__global__ __launch_bounds__(256) void gemm_bt(
    const unsigned short* __restrict__ Ag, const unsigned short* __restrict__ Bg,
    void* __restrict__ Cg_, int N, int Kfix, int lda, int ldb, float scale,
    long long strideA, long long strideB, long long strideC,
    const int* __restrict__ mExt, const int* __restrict__ nExt,
    const int* __restrict__ kDyn) {
  const int b  = blockIdx.z;
  const int bm = blockIdx.y, bn = blockIdx.x;
  if (mExt && bm * 128 >= mExt[b]) return;
  if (nExt && bn * BN >= nExt[b]) return;
  const int K = kDyn ? kDyn[b] : Kfix;

  constexpr int NF = BN / 32;        // B fragments per wave
  __shared__ unsigned short As[128 * 32];
  __shared__ unsigned short Bs[BN * 32];
  const int tid = threadIdx.x;
  const int l = tid & 63, wid = tid >> 6;
  const int wr = wid >> 1, wc = wid & 1;

  const unsigned short* Abf = Ag + (size_t)b * strideA;
  const unsigned short* Bbf = Bg + (size_t)b * strideB;
  const int rowA0 = bm * 128, rowB0 = bn * BN;

  f32x4 acc[4][NF] = {};

  for (int k0 = 0; k0 < K; k0 += 32) {
    // A: 8 chunks of 1 KiB (16 rows x 32 k each); wave stages 2.
#pragma unroll
    for (int i = 0; i < 2; ++i) {
      const int c = wid * 2 + i;
      gload_lds16(Abf + (size_t)(rowA0 + c * 16 + (l >> 2)) * lda + k0 + (l & 3) * 8,
                  &As[c * 512]);
    }
    // B: BN/16 chunks; wave stages 2 (BN=128) or 1 (BN=64).
    if constexpr (BN == 128) {
#pragma unroll
      for (int i = 0; i < 2; ++i) {
        const int c = wid * 2 + i;
        gload_lds16(Bbf + (size_t)(rowB0 + c * 16 + (l >> 2)) * ldb + k0 + (l & 3) * 8,
                    &Bs[c * 512]);
      }
    } else {
      const int c = wid;
      gload_lds16(Bbf + (size_t)(rowB0 + c * 16 + (l >> 2)) * ldb + k0 + (l & 3) * 8,
                  &Bs[c * 512]);
    }
    __syncthreads();

    s16x8 af[4], bfr[NF];
#pragma unroll
    for (int m = 0; m < 4; ++m)
      af[m] = *(const s16x8*)&As[(wr * 64 + m * 16 + (l & 15)) * 32 + (l >> 4) * 8];
#pragma unroll
    for (int n = 0; n < NF; ++n)
      bfr[n] = *(const s16x8*)&Bs[(wc * (BN / 2) + n * 16 + (l & 15)) * 32 + (l >> 4) * 8];
#pragma unroll
    for (int m = 0; m < 4; ++m)
#pragma unroll
      for (int n = 0; n < NF; ++n)
        acc[m][n] = __builtin_amdgcn_mfma_f32_16x16x32_bf16(af[m], bfr[n], acc[m][n], 0, 0, 0);
    __syncthreads();
  }

  const int crow0 = bm * 128 + wr * 64, ccol0 = bn * BN + wc * (BN / 2);
  unsigned short* Cst = nullptr;
  float* Cf = nullptr;
  if constexpr (OUT_BF16)
    Cst = (unsigned short*)Cg_ + (size_t)b * strideC;
  else
    Cf = (float*)Cg_ + (size_t)b * strideC;
#pragma unroll
  for (int m = 0; m < 4; ++m) {
#pragma unroll
    for (int n = 0; n < NF; ++n) {
#pragma unroll
      for (int r = 0; r < 4; ++r) {
        const int row = crow0 + m * 16 + ((l >> 4) << 2) + r;
        const int col = ccol0 + n * 16 + (l & 15);
        const float val = acc[m][n][r] * scale;
        if constexpr (OUT_BF16)
          Cst[(size_t)row * N + col] = f2bf(val);
        else
          Cf[(size_t)row * N + col] = val;
      }
    }
  }
}

// Softmax over compacted cols [0, Lc); cols [Lc, Lcp) get exact 0.
__global__ __launch_bounds__(256) void softmax_c(
    unsigned short* __restrict__ S, const int* __restrict__ Lc,
    const int* __restrict__ Lcp) {
  const int row = blockIdx.x;  // b*T + t, T=1024
  const int b = row >> 10;
  unsigned short* Sr = S + (size_t)row * 2048;
  const int lc = Lc[b], lcp = Lcp[b];
  const int t = threadIdx.x;
  const int j0 = t * 8;
  const bool act = j0 < lcp;

  float v[8];
  if (act) {
    u16x8 raw = *(const u16x8*)(Sr + j0);
#pragma unroll
    for (int j = 0; j < 8; ++j) v[j] = (j0 + j < lc) ? bf2f(raw[j]) : -1.0e30f;
  } else {
#pragma unroll
    for (int j = 0; j < 8; ++j) v[j] = -1.0e30f;
  }

  float mx = -3.0e38f;
#pragma unroll
  for (int j = 0; j < 8; ++j) mx = fmaxf(mx, v[j]);
#pragma unroll
  for (int off = 32; off; off >>= 1) mx = fmaxf(mx, __shfl_xor(mx, off));
  __shared__ float redmx[4];
  __shared__ float redsm[4];
  if ((t & 63) == 0) redmx[t >> 6] = mx;
  __syncthreads();
  mx = fmaxf(fmaxf(redmx[0], redmx[1]), fmaxf(redmx[2], redmx[3]));

  float s = 0.f;
#pragma unroll
  for (int j = 0; j < 8; ++j) {
    v[j] = __expf(v[j] - mx);
    s += v[j];
  }
#pragma unroll
  for (int off = 32; off; off >>= 1) s += __shfl_xor(s, off);
  if ((t & 63) == 0) redsm[t >> 6] = s;
  __syncthreads();
  s = redsm[0] + redsm[1] + redsm[2] + redsm[3];
  const float inv = 1.0f / s;

  if (act) {
    u16x8 o;
#pragma unroll
    for (int j = 0; j < 8; ++j) o[j] = f2bf(v[j] * inv);
    *(u16x8*)(Sr + j0) = o;
  }
}

extern "C" void kernel_launch(void* const* d_in, const int* in_sizes, int n_in,
                              void* d_out, int out_size, void* d_ws, size_t ws_size,
                              hipStream_t stream) {
  const float* H  = (const float*)d_in[0];   // (B, L, Dh)
  const float* G  = (const float*)d_in[1];   // (B, T, Dg)
  const int* mask = (const int*)d_in[2];     // (B, L), nonzero = masked
  const float* Wk = (const float*)d_in[3];   // (P, Dh)
  const float* Wq = (const float*)d_in[4];   // (P, Dg)
  float* Z = (float*)d_out;                  // (B, T, Dh)

  const float SCALE = 0.0625f;  // 256^-0.5
  const size_t MiB = 1024 * 1024;

  char* ws = (char*)d_ws;
  unsigned short* HcT  = (unsigned short*)(ws);             // (B, Dh, L)  32 MiB
  unsigned short* Hc   = (unsigned short*)(ws + 32 * MiB);  // (B, L, Dh)  32 MiB
  unsigned short* Sbuf = Hc;  // alias: Hc dead after Kproj
  unsigned short* Kc   = (unsigned short*)(ws + 64 * MiB);  // (B, L, P)    8 MiB
  unsigned short* Qbuf = (unsigned short*)(ws + 72 * MiB);  // (B, T, P)    4 MiB
  int* idx = (int*)Qbuf;      // alias: idx dead before Qproj writes
  int* Lc  = (int*)(ws + 76 * MiB);
  int* Lcp = Lc + 16;
  unsigned short* Gbf  = (unsigned short*)(ws + 76 * MiB + 4096);  // 12 MiB
  unsigned short* Wkbf = (unsigned short*)(ws + 89 * MiB);         // 0.5 MiB
  unsigned short* Wqbf = (unsigned short*)(ws + 90 * MiB);         // 0.375 MiB

  // 0) scan + casts
  mask_scan<<<dim3(8), 256, 0, stream>>>(mask, idx, Lc, Lcp);
  cast_bf16<<<dim3(1024), 256, 0, stream>>>(G, Gbf, 8 * 1024 * 768 / 4);
  cast_bf16<<<dim3(128), 256, 0, stream>>>(Wk, Wkbf, 256 * 1024 / 4);
  cast_bf16<<<dim3(128), 256, 0, stream>>>(Wq, Wqbf, 256 * 768 / 4);

  // 1) gather unmasked H rows -> Hc + HcT (bf16), zero pad
  gather_cast<<<dim3(32, 16, 8), 256, 0, stream>>>(H, idx, Lc, Lcp, Hc, HcT);

  // 2) Kc = Hc @ Wk^T  (per batch: M = Lcp[b], N = 256, K = 1024)
  gemm_bt<64, true><<<dim3(4, 16, 8), 256, 0, stream>>>(
      Hc, Wkbf, Kc, 256, 1024, 1024, 1024, 1.0f,
      (long long)2048 * 1024, 0, (long long)2048 * 256, Lcp, nullptr, nullptr);

  // 3) Q = G @ Wq^T  (M = 8192, N = 256, K = 768)
  gemm_bt<64, true><<<dim3(4, 64, 1), 256, 0, stream>>>(
      Gbf, Wqbf, Qbuf, 256, 768, 768, 768, 1.0f, 0, 0, 0,
      nullptr, nullptr, nullptr);

  // 4) S = Q @ Kc^T * SCALE  (per batch: M = 1024, N = Lcp[b], K = 256)
  gemm_bt<128, true><<<dim3(16, 8, 8), 256, 0, stream>>>(
      Qbuf, Kc, Sbuf, 2048, 256, 256, 256, SCALE,
      (long long)1024 * 256, (long long)2048 * 256, (long long)1024 * 2048,
      nullptr, Lcp, nullptr);

  // 5) softmax over compacted cols, in place
  softmax_c<<<dim3(8 * 1024), 256, 0, stream>>>(Sbuf, Lc, Lcp);

  // 6) Z = alpha @ Hc  (per batch: M = 1024, N = 1024, K = Lcp[b])
  gemm_bt<128, false><<<dim3(8, 8, 8), 256, 0, stream>>>(
      Sbuf, HcT, Z, 1024, 0, 2048, 2048, 1.0f,
      (long long)1024 * 2048, (long long)1024 * 2048, (long long)1024 * 1024,
      nullptr, nullptr, Lcp);
}